// Round 1
// baseline (473.812 us; speedup 1.0000x reference)
//
#include <hip/hip_runtime.h>
#include <math.h>

// DCNv1 fused: bilinear-sample + grouped GEMM, fp32.
// Shapes (hardcoded per reference): x[4,256,64,64], offset[4,18,64,64],
// weight[256,256,3,3], out[4,256,64,64]. stride=1, pad=1, dil=1, G=DG=1.

constexpr int B  = 4;
constexpr int C  = 256;
constexpr int H  = 64;
constexpr int W  = 64;
constexpr int OC = 256;
constexpr int K  = 9;     // 3x3 taps
constexpr int Ho = 64;
constexpr int Wo = 64;

constexpr int POSB = 32;  // positions (wo) per block
constexpr int CB   = 4;   // channel chunk

// LDS budget: s_w 4*9*256*4 = 36864 B, s_val 4*9*32*4 = 4608 B,
// meta 288*(2*4 + 2*4) = 4608 B  -> ~46 KB -> 3 blocks/CU max (grid gives 2).

__global__ __launch_bounds__(256, 2)
void dcn_fused(const float* __restrict__ x, const float* __restrict__ off,
               const float* __restrict__ wt, float* __restrict__ out)
{
    __shared__ float s_w[CB * K * OC];        // [cl][k][oc]
    __shared__ float s_val[CB][K][POSB];      // sampled columns
    __shared__ float s_lh[K * POSB], s_lw[K * POSB];
    __shared__ int   s_h0[K * POSB], s_w0[K * POSB];

    const int blk = blockIdx.x;                  // 0 .. B*Ho*(Wo/POSB)-1
    const int wob = blk % (Wo / POSB);
    const int ho  = (blk / (Wo / POSB)) % Ho;
    const int b   = blk / ((Wo / POSB) * Ho);
    const int wo0 = wob * POSB;
    const int tid = threadIdx.x;

    // ---- Phase A: per-(tap,pos) sampling metadata (offsets -> corners) ----
    for (int s = tid; s < K * POSB; s += 256) {
        const int p  = s % POSB;
        const int k  = s / POSB;
        const int ki = k / 3, kj = k % 3;
        const int wo = wo0 + p;
        const float dy = off[(((size_t)b * (2 * K) + 2 * k)     * Ho + ho) * Wo + wo];
        const float dx = off[(((size_t)b * (2 * K) + 2 * k + 1) * Ho + ho) * Wo + wo];
        const float ph = (float)(ho - 1 + ki) + dy;
        const float pw = (float)(wo - 1 + kj) + dx;
        const float h0f = floorf(ph), w0f = floorf(pw);
        s_h0[s] = (int)h0f;
        s_w0[s] = (int)w0f;
        s_lh[s] = ph - h0f;
        s_lw[s] = pw - w0f;
    }

    const int toc = tid & 63;   // 0..63  -> oc block of 4
    const int tp  = tid >> 6;   // 0..3   -> pos block of 8
    const int oc0 = toc * 4;
    const int p0  = tp * 8;

    float acc[4][8];
    #pragma unroll
    for (int j = 0; j < 4; ++j)
        #pragma unroll
        for (int p = 0; p < 8; ++p) acc[j][p] = 0.f;

    for (int c0 = 0; c0 < C; c0 += CB) {
        __syncthreads();   // previous chunk's consumers done before overwrite

        // ---- stage weights: w[oc=tid][c0..c0+CB)[k] -> s_w[cl][k][oc] ----
        {
            const float* wp = wt + ((size_t)tid * C + c0) * K;  // 36 contiguous floats
            #pragma unroll
            for (int i = 0; i < CB * K; ++i) {
                s_w[i * OC + tid] = wp[i];   // i = cl*9 + k
            }
        }

        // ---- bilinear-sample CB*K*POSB values into s_val ----
        for (int s = tid; s < CB * K * POSB; s += 256) {
            const int p  = s % POSB;
            const int kk = (s / POSB) % K;
            const int cl = s / (POSB * K);
            const int m  = kk * POSB + p;
            const int h0 = s_h0[m], w0 = s_w0[m];
            const float lh = s_lh[m], lw = s_lw[m];
            const float* xp = x + (size_t)(b * C + c0 + cl) * (H * W);
            const bool h0v = (unsigned)h0       < (unsigned)H;
            const bool h1v = (unsigned)(h0 + 1) < (unsigned)H;
            const bool w0v = (unsigned)w0       < (unsigned)W;
            const bool w1v = (unsigned)(w0 + 1) < (unsigned)W;
            float v00 = 0.f, v01 = 0.f, v10 = 0.f, v11 = 0.f;
            if (h0v && w0v) v00 = xp[h0 * W + w0];
            if (h0v && w1v) v01 = xp[h0 * W + w0 + 1];
            if (h1v && w0v) v10 = xp[(h0 + 1) * W + w0];
            if (h1v && w1v) v11 = xp[(h0 + 1) * W + w0 + 1];
            const float v = (v00 * (1.f - lw) + v01 * lw) * (1.f - lh)
                          + (v10 * (1.f - lw) + v11 * lw) * lh;
            s_val[cl][kk][p] = v;
        }
        __syncthreads();

        // ---- micro-GEMM: 4 oc x 8 pos per thread ----
        #pragma unroll
        for (int cl = 0; cl < CB; ++cl) {
            #pragma unroll
            for (int k = 0; k < K; ++k) {
                const float4 w4 = *reinterpret_cast<const float4*>(&s_w[(cl * K + k) * OC + oc0]);
                float vv[8];
                #pragma unroll
                for (int p = 0; p < 8; ++p) vv[p] = s_val[cl][k][p0 + p];
                #pragma unroll
                for (int p = 0; p < 8; ++p) {
                    acc[0][p] = fmaf(vv[p], w4.x, acc[0][p]);
                    acc[1][p] = fmaf(vv[p], w4.y, acc[1][p]);
                    acc[2][p] = fmaf(vv[p], w4.z, acc[2][p]);
                    acc[3][p] = fmaf(vv[p], w4.w, acc[3][p]);
                }
            }
        }
    }

    // ---- epilogue: contiguous 32B stores per (oc, pos-run) ----
    #pragma unroll
    for (int j = 0; j < 4; ++j) {
        float* op = out + (((size_t)b * OC + oc0 + j) * Ho + ho) * Wo + wo0 + p0;
        float4* op4 = reinterpret_cast<float4*>(op);
        op4[0] = make_float4(acc[j][0], acc[j][1], acc[j][2], acc[j][3]);
        op4[1] = make_float4(acc[j][4], acc[j][5], acc[j][6], acc[j][7]);
    }
}

extern "C" void kernel_launch(void* const* d_in, const int* in_sizes, int n_in,
                              void* d_out, int out_size, void* d_ws, size_t ws_size,
                              hipStream_t stream)
{
    const float* x   = (const float*)d_in[0];
    const float* off = (const float*)d_in[1];
    const float* wt  = (const float*)d_in[2];
    float* out = (float*)d_out;

    const int grid = B * Ho * (Wo / POSB);   // 512
    dcn_fused<<<grid, 256, 0, stream>>>(x, off, wt, out);
}

// Round 2
// 224.735 us; speedup vs baseline: 2.1083x; 2.1083x over previous
//
#include <hip/hip_runtime.h>
#include <hip/hip_bf16.h>
#include <math.h>

// DCNv1 fused, bf16-MFMA version.
// GEMM view: out[oc][pos] = sum_kdim w[oc][kdim] * col[kdim][pos]
//   M = OC = 256, N = B*Ho*Wo = 16384, K = C*9 = 2304
// kdim = tap*256 + c  (tap-major so a 32-wide K-chunk is one tap, 32 channels)
// Block tile: M=256 (all OC) x N=32 positions; grid = 4*64*2 = 512 blocks.
// Per wave: 64 oc x 32 pos = 4x2 MFMA tiles of 16x16 (fp32 acc).

constexpr int B  = 4;
constexpr int C  = 256;
constexpr int H  = 64;
constexpr int W  = 64;
constexpr int OC = 256;
constexpr int Ho = 64;
constexpr int Wo = 64;

constexpr int NT     = 32;   // positions per block
constexpr int CHUNKS = 72;   // 2304 / 32
constexpr int WROW   = 40;   // padded row length (bf16) -> 80 B rows, 2-way banks

typedef __attribute__((ext_vector_type(8))) short bf16x8;
typedef __attribute__((ext_vector_type(4))) float f32x4;

// ---------------- weight pre-pass: fp32 -> bf16, LDS-mirror layout ----------
// wA[chunk][oc][kk] (kk<32: value; kk 32..39: zero pad), row stride WROW.
__global__ void prep_w(const float* __restrict__ wt, ushort* __restrict__ wA)
{
    int t = blockIdx.x * 256 + threadIdx.x;
    if (t >= CHUNKS * OC * WROW) return;
    int kk = t % WROW;
    int oc = (t / WROW) % OC;
    int ch = t / (WROW * OC);
    float v = 0.f;
    if (kk < 32) {
        int tap = ch >> 3;
        int c   = (ch & 7) * 32 + kk;
        v = wt[((size_t)oc * C + c) * 9 + tap];
    }
    __hip_bfloat16 hb = __float2bfloat16(v);
    wA[t] = *(ushort*)&hb;
}

// ---------------- main fused kernel ----------------------------------------
__global__ __launch_bounds__(256, 2)
void dcn_mfma(const float* __restrict__ x, const float* __restrict__ off,
              const ushort* __restrict__ wA_g, float* __restrict__ out)
{
    __shared__ ushort s_wA[OC * WROW];    // 20480 B  weights chunk [oc][40]
    __shared__ ushort s_col[NT * WROW];   //  2560 B  sampled cols  [n][40]
    __shared__ int2   s_midx[9 * NT];     //  2304 B  corner indices (top,bot)
    __shared__ float4 s_mw[9 * NT];       //  4608 B  4 zero-folded corner wts

    const int blk = blockIdx.x;           // b*128 + ho*2 + wob
    const int wob = blk & 1;
    const int ho  = (blk >> 1) & 63;
    const int b   = blk >> 7;
    const int wo0 = wob * NT;
    const int tid = threadIdx.x;

    // ---- Phase A: bilinear meta per (tap, n) --------------------------------
    for (int s = tid; s < 9 * NT; s += 256) {
        const int n   = s & 31;
        const int tap = s >> 5;
        const int wo  = wo0 + n;
        const float dy = off[((size_t)(b * 18 + 2 * tap)     * Ho + ho) * Wo + wo];
        const float dx = off[((size_t)(b * 18 + 2 * tap + 1) * Ho + ho) * Wo + wo];
        const float ph = (float)(ho - 1 + tap / 3) + dy;
        const float pw = (float)(wo - 1 + tap % 3) + dx;
        const float h0f = floorf(ph), w0f = floorf(pw);
        const int h0 = (int)h0f, w0 = (int)w0f;
        const float lh = ph - h0f, lw = pw - w0f;
        // clamp pair base so both 4-B loads stay in-plane; fold validity into wts
        const int wb = min(max(w0, 0), W - 2);
        const int ht = min(max(h0, 0), H - 1);
        const int hb = min(max(h0 + 1, 0), H - 1);
        const float s0 = (wb == w0) ? (1.f - lw) : ((wb == w0 + 1) ? lw : 0.f);
        const float s1 = (wb + 1 == w0 + 1) ? lw : ((wb + 1 == w0) ? (1.f - lw) : 0.f);
        const float wtp = (h0 >= 0 && h0 < H)         ? (1.f - lh) : 0.f;
        const float wbt = (h0 + 1 >= 0 && h0 + 1 < H) ? lh         : 0.f;
        s_midx[s] = make_int2(ht * W + wb, hb * W + wb);
        s_mw[s]   = make_float4(wtp * s0, wtp * s1, wbt * s0, wbt * s1);
    }

    const int lane = tid & 63;
    const int wv   = tid >> 6;        // wave id: oc 64*wv .. +63
    const int kq   = lane >> 4;       // 0..3
    const int mr   = lane & 15;

    f32x4 acc[4][2];
    #pragma unroll
    for (int mt = 0; mt < 4; ++mt)
        #pragma unroll
        for (int nt = 0; nt < 2; ++nt)
            acc[mt][nt] = (f32x4){0.f, 0.f, 0.f, 0.f};

    const int sn = tid & 31;          // sampling: position
    const int sg = tid >> 5;          // sampling: channel group (4 ch each)

    for (int ch = 0; ch < CHUNKS; ++ch) {
        __syncthreads();  // prior chunk's MFMA reads done before overwrite

        // ---- stage weight chunk: 80 B/thread, copy-through ----
        {
            const uint4* src = (const uint4*)(wA_g + (size_t)ch * OC * WROW) + tid * 5;
            uint4* dst = (uint4*)s_wA + tid * 5;
            #pragma unroll
            for (int i = 0; i < 5; ++i) dst[i] = src[i];
        }

        // ---- sample 32 pos x 32 channels -> s_col (4 samples/thread) ----
        {
            const int tap = ch >> 3;
            const int c0  = (ch & 7) * 32;
            const int2   mi = s_midx[tap * NT + sn];
            const float4 mw = s_mw[tap * NT + sn];
            ushort4 pk;
            #pragma unroll
            for (int i = 0; i < 4; ++i) {
                const float* xp = x + ((size_t)(b * C + c0 + sg * 4 + i) << 12);
                const float v = mw.x * xp[mi.x] + mw.y * xp[mi.x + 1]
                              + mw.z * xp[mi.y] + mw.w * xp[mi.y + 1];
                __hip_bfloat16 hb = __float2bfloat16(v);
                ((ushort*)&pk)[i] = *(ushort*)&hb;
            }
            *(ushort4*)&s_col[sn * WROW + sg * 4] = pk;
        }
        __syncthreads();

        // ---- MFMA: 4 M-tiles x 2 N-tiles per wave ----
        bf16x8 bfr[2];
        #pragma unroll
        for (int nt = 0; nt < 2; ++nt)
            bfr[nt] = *(const bf16x8*)&s_col[(nt * 16 + mr) * WROW + kq * 8];
        #pragma unroll
        for (int mt = 0; mt < 4; ++mt) {
            const bf16x8 afr = *(const bf16x8*)&s_wA[(wv * 64 + mt * 16 + mr) * WROW + kq * 8];
            acc[mt][0] = __builtin_amdgcn_mfma_f32_16x16x32_bf16(afr, bfr[0], acc[mt][0], 0, 0, 0);
            acc[mt][1] = __builtin_amdgcn_mfma_f32_16x16x32_bf16(afr, bfr[1], acc[mt][1], 0, 0, 0);
        }
    }

    // ---- epilogue: C/D layout col = lane&15, row = (lane>>4)*4 + r ----
    #pragma unroll
    for (int mt = 0; mt < 4; ++mt) {
        #pragma unroll
        for (int nt = 0; nt < 2; ++nt) {
            #pragma unroll
            for (int r = 0; r < 4; ++r) {
                const int oc = wv * 64 + mt * 16 + kq * 4 + r;
                const int wo = wo0 + nt * 16 + mr;
                out[((size_t)(b * OC + oc) * Ho + ho) * Wo + wo] = acc[mt][nt][r];
            }
        }
    }
}

extern "C" void kernel_launch(void* const* d_in, const int* in_sizes, int n_in,
                              void* d_out, int out_size, void* d_ws, size_t ws_size,
                              hipStream_t stream)
{
    const float* x   = (const float*)d_in[0];
    const float* off = (const float*)d_in[1];
    const float* wt  = (const float*)d_in[2];
    float* out = (float*)d_out;
    ushort* wA = (ushort*)d_ws;   // needs 72*256*40*2 = 1.47 MB

    const int prep_total = CHUNKS * OC * WROW;
    prep_w<<<(prep_total + 255) / 256, 256, 0, stream>>>(wt, wA);

    const int grid = B * Ho * (Wo / NT);  // 512
    dcn_mfma<<<grid, 256, 0, stream>>>(x, off, wA, out);
}

// Round 4
// 196.403 us; speedup vs baseline: 2.4124x; 1.1443x over previous
//
#include <hip/hip_runtime.h>
#include <hip/hip_bf16.h>
#include <math.h>

// DCNv1 fused, bf16-MFMA, round 4: round-2 serial loop (known good) +
// XCD swizzle + NT=64 tile + coalesced prep_w. No software pipeline.
//
// GEMM view: out[oc][pos] = sum_k w[oc][k] * col[k][pos]
//   M = OC = 256, N = B*Ho*Wo = 16384, K = C*9 = 2304, kdim = tap*256 + c
// Block: 256 thr (4 waves), tile M=256 x N=64 (one wo row). grid = 256.
// Per wave per 32-K chunk: 4x4 MFMA tiles (16x16x32 bf16), fp32 acc.

constexpr int B  = 4;
constexpr int C  = 256;
constexpr int H  = 64;
constexpr int W  = 64;
constexpr int OC = 256;
constexpr int Ho = 64;
constexpr int Wo = 64;

constexpr int NT     = 64;   // positions per block (full row)
constexpr int CHUNKS = 72;   // 2304 / 32
constexpr int WROW   = 40;   // padded row (bf16): 80 B rows, breaks pow2 banks

typedef __attribute__((ext_vector_type(8))) short bf16x8;
typedef __attribute__((ext_vector_type(4))) float f32x4;

// ---- weight pre-pass: fp32 -> bf16 in LDS-mirror layout wA[ch][oc][40] ----
// thread per (oc,c): reads 9 contiguous floats (coalesced-ish), scatters bf16.
__global__ __launch_bounds__(256)
void prep_w(const float* __restrict__ wt, ushort* __restrict__ wA)
{
    const int t = blockIdx.x * 256 + threadIdx.x;   // over OC*C = 65536
    if (t >= OC * C) return;
    const int c   = t & (C - 1);
    const int oc  = t >> 8;
    const int chb = c >> 5;      // channel-group within tap
    const int kk  = c & 31;
    const float* wp = wt + (size_t)t * 9;           // 36 contiguous bytes
    #pragma unroll
    for (int tap = 0; tap < 9; ++tap) {
        __hip_bfloat16 hb = __float2bfloat16(wp[tap]);
        wA[((size_t)(tap * 8 + chb) * OC + oc) * WROW + kk] = *(ushort*)&hb;
    }
    if (kk < 8) {   // zero the 8-entry row pad
        #pragma unroll
        for (int tap = 0; tap < 9; ++tap)
            wA[((size_t)(tap * 8 + chb) * OC + oc) * WROW + 32 + kk] = 0;
    }
}

// ---------------- main fused kernel ----------------------------------------
__global__ __launch_bounds__(256, 1)
void dcn_mfma(const float* __restrict__ x, const float* __restrict__ off,
              const ushort* __restrict__ wA_g, float* __restrict__ out)
{
    __shared__ __align__(16) ushort s_wA[OC * WROW];   // 20480 B
    __shared__ __align__(16) ushort s_col[NT * WROW];  //  5120 B
    __shared__ int2   s_midx[9 * NT];                  //  4608 B
    __shared__ float4 s_mw[9 * NT];                    //  9216 B

    // XCD swizzle: blocks resident on one XCD share batch b and a ho-half,
    // so x[b]-half (~2.1 MB) + weights (1.47 MB) fit the 4 MB per-XCD L2.
    const int xcd = blockIdx.x & 7;
    const int ii  = blockIdx.x >> 3;            // 0..31
    const int b   = xcd & 3;
    const int ho  = ((xcd >> 2) << 5) + ii;     // half*32 + ii
    const int tid = threadIdx.x;

    // ---- Phase A: bilinear meta per (tap, n); zero-fold padding into wts ----
    for (int s = tid; s < 9 * NT; s += 256) {
        const int n   = s & 63;
        const int tap = s >> 6;
        const float dy = off[((size_t)(b * 18 + 2 * tap)     * Ho + ho) * Wo + n];
        const float dx = off[((size_t)(b * 18 + 2 * tap + 1) * Ho + ho) * Wo + n];
        const float ph = (float)(ho - 1 + tap / 3) + dy;
        const float pw = (float)(n  - 1 + tap % 3) + dx;
        const float h0f = floorf(ph), w0f = floorf(pw);
        const int h0 = (int)h0f, w0 = (int)w0f;
        const float lh = ph - h0f, lw = pw - w0f;
        const int wb = min(max(w0, 0), W - 2);      // pair base stays in-plane
        const int ht = min(max(h0, 0), H - 1);
        const int hb = min(max(h0 + 1, 0), H - 1);
        const float s0 = (wb == w0) ? (1.f - lw) : ((wb == w0 + 1) ? lw : 0.f);
        const float s1 = (wb + 1 == w0 + 1) ? lw : ((wb + 1 == w0) ? (1.f - lw) : 0.f);
        const float wtp = (h0 >= 0 && h0 < H)         ? (1.f - lh) : 0.f;
        const float wbt = (h0 + 1 >= 0 && h0 + 1 < H) ? lh         : 0.f;
        s_midx[s] = make_int2(ht * W + wb, hb * W + wb);
        s_mw[s]   = make_float4(wtp * s0, wtp * s1, wbt * s0, wbt * s1);
    }

    const int lane = tid & 63;
    const int wv   = tid >> 6;        // wave -> oc block of 64
    const int kq   = lane >> 4;
    const int mr   = lane & 15;
    const int sn   = tid & 63;        // sampling: position
    const int sg   = tid >> 6;        // sampling: channel octet

    f32x4 acc[4][4];
    #pragma unroll
    for (int mt = 0; mt < 4; ++mt)
        #pragma unroll
        for (int nt = 0; nt < 4; ++nt)
            acc[mt][nt] = (f32x4){0.f, 0.f, 0.f, 0.f};

    for (int ch = 0; ch < CHUNKS; ++ch) {
        __syncthreads();   // prior chunk's MFMA reads done before overwrite

        // ---- stage weight chunk: 80 B/thread, copy-through ----
        {
            const uint4* src = (const uint4*)(wA_g + (size_t)ch * OC * WROW) + tid * 5;
            uint4* dst = (uint4*)s_wA + tid * 5;
            #pragma unroll
            for (int i = 0; i < 5; ++i) dst[i] = src[i];
        }

        // ---- sample 64 pos x 32 channels -> s_col (8 channels/thread) ----
        {
            const int tap = ch >> 3;
            const int c0  = (ch & 7) << 5;
            const int2   mi = s_midx[tap * NT + sn];
            const float4 mw = s_mw[tap * NT + sn];
            union { ushort pk[8]; uint4 v; } u;
            #pragma unroll
            for (int i = 0; i < 8; ++i) {
                const float* xp = x + ((size_t)(b * C + c0 + sg * 8 + i) << 12);
                const float v = mw.x * xp[mi.x] + mw.y * xp[mi.x + 1]
                              + mw.z * xp[mi.y] + mw.w * xp[mi.y + 1];
                __hip_bfloat16 hb = __float2bfloat16(v);
                u.pk[i] = *(ushort*)&hb;
            }
            *(uint4*)&s_col[sn * WROW + sg * 8] = u.v;
        }
        __syncthreads();

        // ---- MFMA: 4 M-tiles x 4 N-tiles per wave ----
        bf16x8 bfr[4];
        #pragma unroll
        for (int nt = 0; nt < 4; ++nt)
            bfr[nt] = *(const bf16x8*)&s_col[(nt * 16 + mr) * WROW + kq * 8];
        #pragma unroll
        for (int mt = 0; mt < 4; ++mt) {
            const bf16x8 afr = *(const bf16x8*)&s_wA[(wv * 64 + mt * 16 + mr) * WROW + kq * 8];
            #pragma unroll
            for (int nt = 0; nt < 4; ++nt)
                acc[mt][nt] = __builtin_amdgcn_mfma_f32_16x16x32_bf16(afr, bfr[nt], acc[mt][nt], 0, 0, 0);
        }
    }

    // ---- epilogue: C/D layout col = lane&15 (pos), row = kq*4 + r (oc) ----
    #pragma unroll
    for (int mt = 0; mt < 4; ++mt)
        #pragma unroll
        for (int nt = 0; nt < 4; ++nt)
            #pragma unroll
            for (int r = 0; r < 4; ++r) {
                const int oc = wv * 64 + mt * 16 + kq * 4 + r;
                const int wo = nt * 16 + mr;
                out[((size_t)(b * OC + oc) * Ho + ho) * Wo + wo] = acc[mt][nt][r];
            }
}

extern "C" void kernel_launch(void* const* d_in, const int* in_sizes, int n_in,
                              void* d_out, int out_size, void* d_ws, size_t ws_size,
                              hipStream_t stream)
{
    const float* x   = (const float*)d_in[0];
    const float* off = (const float*)d_in[1];
    const float* wt  = (const float*)d_in[2];
    float* out = (float*)d_out;
    ushort* wA = (ushort*)d_ws;   // 72*256*40*2 = 1.47 MB

    prep_w<<<(OC * C + 255) / 256, 256, 0, stream>>>(wt, wA);
    dcn_mfma<<<B * Ho, 256, 0, stream>>>(x, off, wA, out);   // 256 blocks
}